// Round 15
// baseline (74.367 us; speedup 1.0000x reference)
//
#include <hip/hip_runtime.h>
#include <hip/hip_bf16.h>

#define N 8192
#define DIMS 128
#define NT 64                        // 64 tiles of 128 rows/cols
#define TILE 128
#define NBLK (NT * (NT + 1) / 2)     // 2080 triangular blocks
#define SUBTILES 8                   // 8 x 16-col subtiles per block
#define NSTEPS 4                     // 32 cols per double-buffer step
#define STRIPS 2                     // 16-row strips per wave (32 rows/wave)
#define NFIN 2048
#define MARGIN_F 0.2f
#define EPS_F 1e-6f
#define COLMETA_LDS 16384            // after 2x8KB B double buffer
#define BUFT_LDS 17408               // transposed per-wave partials (4x128 uint2)
#define INF_F __builtin_huge_valf()

typedef __bf16 bf16x8 __attribute__((ext_vector_type(8)));
typedef float f32x4 __attribute__((ext_vector_type(4)));

// ws layout (bytes), ws_size = 256 MiB:
//   Xb   : ushort[N*DIMS]  @ 0        (2 MiB)  bf16 features (A side)
//   Xneg : ushort[N*DIMS]  @ 2097152  (2 MiB)  negated bf16 features (B side)
//   meta : float2[N]       @ 4194304  (64 KiB) {0.5*(512+sq), label bits}
//   part : uint2[64*N]     @ 4259840  (4 MiB)  packed {max_pos_u, min_neg_u}
//   bsum : float2[NFIN]    @ 8454144  (16 KiB)
#define XB_OFF   0
#define XNEG_OFF 2097152
#define META_OFF 4194304
#define PART_OFF 4259840
#define BSUM_OFF 8454144

#define GLD_LDS(g, l) \
  __builtin_amdgcn_global_load_lds( \
      (const __attribute__((address_space(1))) void*)(g), \
      (__attribute__((address_space(3))) void*)(l), 16, 0, 0)

// ---------------- prep: fp32 -> bf16 (+negated copy), meta ---------------
// meta.x = 0.5*(512 + sq_j). With B = -X and MFMA C-init = meta.x of the
// col, acc = 0.5*(512+sq_col) - dot = key/2 > 0 (Cauchy-Schwarz + bias).
__global__ __launch_bounds__(256) void prep_kernel(
    const float* __restrict__ feat, const int* __restrict__ lab,
    unsigned short* __restrict__ Xb, unsigned short* __restrict__ Xneg,
    float2* __restrict__ meta) {
  int row = blockIdx.x * 4 + (threadIdx.x >> 6);
  int lane = threadIdx.x & 63;
  float2 x = *reinterpret_cast<const float2*>(feat + (size_t)row * DIMS + lane * 2);
  __hip_bfloat16 hx = __float2bfloat16(x.x);
  __hip_bfloat16 hy = __float2bfloat16(x.y);
  unsigned short ux, uy;
  __builtin_memcpy(&ux, &hx, 2);
  __builtin_memcpy(&uy, &hy, 2);
  unsigned int packed = (unsigned int)ux | ((unsigned int)uy << 16);
  *reinterpret_cast<unsigned int*>(Xb + (size_t)row * DIMS + lane * 2) = packed;
  *reinterpret_cast<unsigned int*>(Xneg + (size_t)row * DIMS + lane * 2) =
      packed ^ 0x80008000u;  // bf16 sign-flip both halves
  float s = x.x * x.x + x.y * x.y;
#pragma unroll
  for (int m = 32; m >= 1; m >>= 1) s += __shfl_xor(s, m, 64);
  if (lane == 0)
    meta[row] = make_float2(0.5f * (s + 512.0f), __int_as_float(lab[row]));
}

// ---------------- mine: SYMMETRIC triangular MFMA + dual-direction mining -
// Block (rb<=cb): rows rb*128..+128 (A), cols cb*128..+128 (B from Xneg).
// Direct mining (anchor=row, cand=col) as r12; transposed mining
// (anchor=col, cand=row) via key_T/2 = acc + (h_row - h_col) = h_row - dot,
// per-wave partials merged in LDS. Anchor in tile t: direct slots cb>=t,
// transposed slots rb<t -> 64 disjoint slots. Halves MFMA/LDS/staging work.
__global__ __launch_bounds__(256, 4) void mine_kernel(
    const unsigned short* __restrict__ Xb, const unsigned short* __restrict__ Xneg,
    const float2* __restrict__ meta, uint2* __restrict__ part) {
  __shared__ char smem[2 * 8192 + 1024 + 4096];  // B dbuf + colmeta + bufT

  // --- triangular decode: blockIdx.x -> (rb, cb), rb <= cb ---
  int k = blockIdx.x;
  int rb = (int)floorf((float)NT + 0.5f -
                       sqrtf(((float)NT + 0.5f) * ((float)NT + 0.5f) - 2.0f * (float)k));
  if (rb < 0) rb = 0;
  while (rb > 0 && rb * NT - rb * (rb - 1) / 2 > k) --rb;
  while ((rb + 1) * NT - (rb + 1) * rb / 2 <= k) ++rb;
  int cb = rb + (k - (rb * NT - rb * (rb - 1) / 2));
  bool doT = (rb != cb);

  int tid = threadIdx.x;
  int wave = tid >> 6;
  int lane = tid & 63;
  int lrow = lane & 15;  // B-col / C-col lane index
  int lk = lane >> 4;    // k-subgroup; also C-row group
  int rowbase = rb * TILE + wave * (STRIPS * 16);
  int j0 = cb * TILE;

  // --- stage col meta (128 * 8B = 1KB): wave 0 ---
  if (tid < 64) {
    const char* g = (const char*)meta + (size_t)j0 * 8 + tid * 16;
    char* l = smem + COLMETA_LDS;
    GLD_LDS(g, l);
  }
  // --- B staging (Xneg): tid -> (colt = tid>>4, chunk = tid&15); each step
  // stages 32 cols (8KB) = cols {colt, colt+16}. Involution swizzle
  // chunk^(col&7); col&7 invariant under +16/+32 col offsets.
  int colt = tid >> 4;
  int chunk = tid & 15;
  const char* gsrc0 = (const char*)Xneg + (size_t)(j0 + colt) * 256 +
                      ((chunk ^ (colt & 7)) * 16);
  {  // stage step 0 into buf 0
    GLD_LDS(gsrc0, smem + wave * 1024);
    GLD_LDS(gsrc0 + 4096, smem + 4096 + wave * 1024);
  }

  // --- A fragments + row meta (h, label) in registers ---
  bf16x8 afrag[STRIPS][4];
#pragma unroll
  for (int s = 0; s < STRIPS; ++s) {
    const unsigned short* rp = Xb + (size_t)(rowbase + s * 16 + lrow) * DIMS;
#pragma unroll
    for (int g = 0; g < 4; ++g)
      afrag[s][g] = *reinterpret_cast<const bf16x8*>(rp + g * 32 + lk * 8);
  }
  float hrow_[STRIPS][4];
  int labr[STRIPS][4];
#pragma unroll
  for (int s = 0; s < STRIPS; ++s)
#pragma unroll
    for (int e = 0; e < 4; ++e) {
      float2 rm = meta[rowbase + s * 16 + lk * 4 + e];
      hrow_[s][e] = rm.x;
      labr[s][e] = __float_as_int(rm.y);
    }

  unsigned int bpu[STRIPS][4], bnu[STRIPS][4];
#pragma unroll
  for (int s = 0; s < STRIPS; ++s)
#pragma unroll
    for (int e = 0; e < 4; ++e) { bpu[s][e] = 0u; bnu[s][e] = 0xFFFFFFFFu; }

  int boff[4];
#pragma unroll
  for (int g = 0; g < 4; ++g)
    boff[g] = lrow * 256 + (((g * 4 + lk) ^ (lrow & 7)) * 16);

  __syncthreads();  // colmeta + step0 staged

  for (int it = 0; it < NSTEPS; ++it) {
    int cur = it & 1;
    if (it + 1 < NSTEPS) {  // prefetch next 32 cols
      const char* g = gsrc0 + (size_t)(it + 1) * 8192;
      char* l = smem + (cur ^ 1) * 8192 + wave * 1024;
      GLD_LDS(g, l);
      GLD_LDS(g + 4096, l + 4096);
    }

#pragma unroll
    for (int h = 0; h < 2; ++h) {
      int t = it * 2 + h;
      int cloc = t * 16 + lrow;
      float2 cm =
          *reinterpret_cast<const float2*>(smem + COLMETA_LDS + cloc * 8);
      float hcol = cm.x;  // 0.5*(512+sq_col)
      int labc = __float_as_int(cm.y);
      unsigned int juc = (unsigned int)(j0 + cloc);

      const char* bbase = smem + cur * 8192 + h * 4096;
      bf16x8 bb[4];
#pragma unroll
      for (int g = 0; g < 4; ++g)
        bb[g] = *reinterpret_cast<const bf16x8*>(bbase + boff[g]);

      unsigned int tpu = 0u, tnu = 0xFFFFFFFFu;  // transposed, this col
#pragma unroll
      for (int s = 0; s < STRIPS; ++s) {
        f32x4 acc = {hcol, hcol, hcol, hcol};  // C-init: acc = key/2
#pragma unroll
        for (int g = 0; g < 4; ++g)
          acc = __builtin_amdgcn_mfma_f32_16x16x32_bf16(afrag[s][g], bb[g], acc,
                                                        0, 0, 0);
#pragma unroll
        for (int e = 0; e < 4; ++e) {
          bool pos = (labc == labr[s][e]);
          // direct: anchor=row, candidate=col
          unsigned int u = (__float_as_uint(acc[e]) & 0xFFFFE000u) | juc;
          unsigned int up = pos ? u : 0u;
          unsigned int un = pos ? 0xFFFFFFFFu : u;
          bpu[s][e] = max(bpu[s][e], up);
          bnu[s][e] = min(bnu[s][e], un);
          // transposed: anchor=col, candidate=row; key_T/2 = h_row - dot
          float kT = acc[e] + (hrow_[s][e] - hcol);
          unsigned int jur = (unsigned int)(rowbase + s * 16 + lk * 4 + e);
          unsigned int uT = (__float_as_uint(kT) & 0xFFFFE000u) | jur;
          unsigned int utp = pos ? uT : 0u;
          unsigned int utn = pos ? 0xFFFFFFFFu : uT;
          tpu = max(tpu, utp);
          tnu = min(tnu, utn);
        }
      }
      // merge transposed across lk groups (lanes lrow, +16, +32, +48)
      tpu = max(tpu, (unsigned int)__shfl_xor((int)tpu, 16, 64));
      tnu = min(tnu, (unsigned int)__shfl_xor((int)tnu, 16, 64));
      tpu = max(tpu, (unsigned int)__shfl_xor((int)tpu, 32, 64));
      tnu = min(tnu, (unsigned int)__shfl_xor((int)tnu, 32, 64));
      if (doT && lane < 16)
        *reinterpret_cast<uint2*>(smem + BUFT_LDS + (wave * 128 + cloc) * 8) =
            make_uint2(tpu, tnu);
    }
    // drains stage-loads (vmcnt) + ds_reads (lgkm), then barrier.
    __syncthreads();
  }

  // --- direct epilogue: merge across 16 lanes sharing each C-row ---
#pragma unroll
  for (int s = 0; s < STRIPS; ++s) {
#pragma unroll
    for (int e = 0; e < 4; ++e) {
      unsigned int pu = bpu[s][e], nu = bnu[s][e];
#pragma unroll
      for (int m = 1; m < 16; m <<= 1) {
        pu = max(pu, (unsigned int)__shfl_xor((int)pu, m, 64));
        nu = min(nu, (unsigned int)__shfl_xor((int)nu, m, 64));
      }
      if (lrow == 0) {
        int row = rowbase + s * 16 + lk * 4 + e;
        part[(size_t)cb * N + row] = make_uint2(pu, nu);
      }
    }
  }

  // --- transposed epilogue: merge 4 wave-partials per col (bufT written
  // before the loop's final __syncthreads) ---
  if (doT && tid < 128) {
    uint2 a0 = *reinterpret_cast<uint2*>(smem + BUFT_LDS + (0 * 128 + tid) * 8);
    uint2 a1 = *reinterpret_cast<uint2*>(smem + BUFT_LDS + (1 * 128 + tid) * 8);
    uint2 a2 = *reinterpret_cast<uint2*>(smem + BUFT_LDS + (2 * 128 + tid) * 8);
    uint2 a3 = *reinterpret_cast<uint2*>(smem + BUFT_LDS + (3 * 128 + tid) * 8);
    unsigned int pu = max(max(a0.x, a1.x), max(a2.x, a3.x));
    unsigned int nu = min(min(a0.y, a1.y), min(a2.y, a3.y));
    part[(size_t)rb * N + j0 + tid] = make_uint2(pu, nu);
  }
}

// ---------------- finalize: 64-slot lane-per-slot merge + exact hinge -----
__global__ __launch_bounds__(256) void finalize_kernel(
    const float* __restrict__ feat, const uint2* __restrict__ part,
    float2* __restrict__ bsum) {
  int wave = threadIdx.x >> 6, lane = threadIdx.x & 63;
  int i = blockIdx.x * 4 + wave;

  uint2 p = part[(size_t)lane * N + i];
  unsigned int pu = p.x, nu = p.y;
#pragma unroll
  for (int m = 1; m < 64; m <<= 1) {
    pu = max(pu, (unsigned int)__shfl_xor((int)pu, m, 64));
    nu = min(nu, (unsigned int)__shfl_xor((int)nu, m, 64));
  }
  pu = (unsigned int)__shfl((int)pu, 0, 64);
  nu = (unsigned int)__shfl((int)nu, 0, 64);
  bool valid = (nu != 0xFFFFFFFFu);
  int pi = (int)(pu & 8191u);
  int ni = (int)(nu & 8191u);

  float2 av = *reinterpret_cast<const float2*>(feat + (size_t)i * DIMS + lane * 2);
  float2 pw = *reinterpret_cast<const float2*>(feat + (size_t)pi * DIMS + lane * 2);
  float2 nw = *reinterpret_cast<const float2*>(feat + (size_t)ni * DIMS + lane * 2);
  float d0 = av.x - pw.x + EPS_F, d1 = av.y - pw.y + EPS_F;
  float sp = fmaf(d0, d0, d1 * d1);
  float e0 = av.x - nw.x + EPS_F, e1 = av.y - nw.y + EPS_F;
  float sn = fmaf(e0, e0, e1 * e1);
#pragma unroll
  for (int m = 32; m >= 1; m >>= 1) {
    sp += __shfl_xor(sp, m, 64);
    sn += __shfl_xor(sn, m, 64);
  }

  __shared__ float s_s[4], s_c[4];
  if (lane == 0) {
    float per = sqrtf(sp) - sqrtf(sn) + MARGIN_F;
    per = per > 0.f ? per : 0.f;
    per = valid ? per : 0.f;
    s_s[wave] = per;
    s_c[wave] = valid ? 1.f : 0.f;
  }
  __syncthreads();
  if (threadIdx.x == 0) {
    float ts = (s_s[0] + s_s[1]) + (s_s[2] + s_s[3]);
    float tc = (s_c[0] + s_c[1]) + (s_c[2] + s_c[3]);
    bsum[blockIdx.x] = make_float2(ts, tc);
  }
}

__global__ __launch_bounds__(256) void final_reduce_kernel(
    const float2* __restrict__ bsum, float* __restrict__ out) {
  int t = threadIdx.x;
  float s = 0.f, c = 0.f;
#pragma unroll
  for (int k = 0; k < NFIN / 256; ++k) {
    float2 v = bsum[t + k * 256];
    s += v.x; c += v.y;
  }
#pragma unroll
  for (int m = 32; m >= 1; m >>= 1) {
    s += __shfl_xor(s, m, 64);
    c += __shfl_xor(c, m, 64);
  }
  __shared__ float s_s[4], s_c[4];
  int wave = t >> 6, lane = t & 63;
  if (lane == 0) { s_s[wave] = s; s_c[wave] = c; }
  __syncthreads();
  if (t == 0) {
    float ts = (s_s[0] + s_s[1]) + (s_s[2] + s_s[3]);
    float tc = (s_c[0] + s_c[1]) + (s_c[2] + s_c[3]);
    out[0] = (tc > 0.f) ? (ts / tc) : 0.f;
  }
}

extern "C" void kernel_launch(void* const* d_in, const int* in_sizes, int n_in,
                              void* d_out, int out_size, void* d_ws, size_t ws_size,
                              hipStream_t stream) {
  const float* feat = (const float*)d_in[0];
  const int* lab = (const int*)d_in[1];
  char* ws = (char*)d_ws;
  unsigned short* Xb = (unsigned short*)(ws + XB_OFF);
  unsigned short* Xneg = (unsigned short*)(ws + XNEG_OFF);
  float2* meta = (float2*)(ws + META_OFF);
  uint2* part = (uint2*)(ws + PART_OFF);
  float2* bsum = (float2*)(ws + BSUM_OFF);
  float* out = (float*)d_out;

  prep_kernel<<<N / 4, 256, 0, stream>>>(feat, lab, Xb, Xneg, meta);
  mine_kernel<<<NBLK, 256, 0, stream>>>(Xb, Xneg, meta, part);
  finalize_kernel<<<N / 4, 256, 0, stream>>>(feat, part, bsum);
  final_reduce_kernel<<<1, 256, 0, stream>>>(bsum, out);
}